// Round 2
// baseline (1730.468 us; speedup 1.0000x reference)
//
#include <hip/hip_runtime.h>

typedef unsigned short u16;
typedef unsigned int   u32;
typedef short bf16x8 __attribute__((ext_vector_type(8)));
typedef float f32x4  __attribute__((ext_vector_type(4)));

// ---------- geometry ----------
#define Bn   2
#define Nn   7
#define Cc   128
#define Hh   120
#define Ww   360
#define HW   43200          // Hh*Ww
#define PIX  86400          // Bn*HW
#define HP   122            // padded H (h index +1)
#define WP   362            // padded W (w index +1)
#define ICP1 928            // 29*32 (898 real + pad)
#define NCH1 29
#define ICP2 192            // 6*32  (176 real + pad)
#define NCH2 6

// ---------- ws layout (bytes, 256-aligned) ----------
constexpr size_t AL(size_t x){ return (x + 255) & ~size_t(255); }
constexpr size_t XH_BYTES  = (size_t)Bn*HP*WP*ICP1*2;      // ~163.9 MB
constexpr size_t LRS_BYTES = (size_t)Bn*HP*WP*ICP2*2;      // ~33.9 MB
constexpr size_t OFF_XH  = 0;
constexpr size_t OFF_LRS = AL(OFF_XH + XH_BYTES + 65536);     // slack for conv A-tile overrun
constexpr size_t OFF_FEAT= AL(OFF_LRS + LRS_BYTES + 65536);   // feat aliases mh (mh dead before conv)
constexpr size_t OFF_W1F = AL(OFF_FEAT + (size_t)PIX*128*2);
constexpr size_t OFF_W2F = AL(OFF_W1F + (size_t)9*NCH1*128*32*2);
constexpr size_t OFF_W2B = AL(OFF_W2F + (size_t)9*NCH2*64*32*2);
constexpr size_t OFF_CN  = AL(OFF_W2B + 256);
constexpr size_t OFF_GST = AL(OFF_CN + (size_t)PIX*4);
// offsets buffer (f32, PIX*64*4 = 22.1MB) aliases xh (xh dead after main conv)

// ---------- helpers ----------
__device__ __forceinline__ float bf2f(u16 h){ union{u32 u; float f;} c; c.u = ((u32)h)<<16; return c.f; }
__device__ __forceinline__ u16 f2bf(float f){
  union{float f; u32 u;} c; c.f = f;
  u32 r = (c.u + 0x7FFFu + ((c.u>>16)&1u)) >> 16;
  return (u16)r;
}
__device__ __forceinline__ float bflo(u32 a){ union{u32 u; float f;} c; c.u = a<<16;          return c.f; }
__device__ __forceinline__ float bfhi(u32 a){ union{u32 u; float f;} c; c.u = a & 0xffff0000u; return c.f; }

__device__ __forceinline__ void gl_lds16(const u16* g, u16* l){
  __builtin_amdgcn_global_load_lds((const __attribute__((address_space(1))) void*)g,
                                   (__attribute__((address_space(3))) void*)l, 16, 0, 0);
}

// ---------- init: zero gstats + spatial pads of xh / lrs ----------
__global__ __launch_bounds__(256) void k_init(u16* __restrict__ xh, u16* __restrict__ lrs, float* __restrict__ gstats)
{
  int t = blockIdx.x*256 + threadIdx.x;
  if (t < 64) gstats[t] = 0.f;
  t -= 64;
  if (t < 0 || t >= 2*964*140) return;
  int b = t / (964*140); int r = t - b*(964*140);
  int i = r / 140, chunk = r - i*140;
  int hp, wp;
  if (i < 362)      { hp = 0;   wp = i; }
  else if (i < 724) { hp = 121; wp = i-362; }
  else { int j = i-724; hp = 1 + (j>>1); wp = (j&1) ? 361 : 0; }
  size_t pixel = (size_t)(b*HP + hp)*WP + wp;
  uint4 z = make_uint4(0,0,0,0);
  if (chunk < 116) ((uint4*)(xh  + pixel*ICP1))[chunk]      = z;
  else             ((uint4*)(lrs + pixel*ICP2))[chunk-116]  = z;
}

// ---------- weight prep: MFMA-fragment-ordered  [tap][chunk][oc][32] ----------
__global__ __launch_bounds__(256) void k_prep_w1(const float* __restrict__ cw, u16* __restrict__ w1f)
{
  int t = blockIdx.x*256 + threadIdx.x;      // 9*29*128*32
  int kk = t & 31; int rest = t >> 5;
  int oc = rest & 127; rest >>= 7;           // rest = tap*29 + c
  int c = rest % NCH1, tap = rest / NCH1;
  int ic = c*32 + kk;
  u16 v = 0;
  if (ic < 898) v = f2bf(cw[(size_t)oc*8082 + (size_t)ic*9 + tap]);
  w1f[t] = v;
}

__global__ __launch_bounds__(256) void k_prep_w2(const float* __restrict__ ow0, const float* __restrict__ ow1,
    const float* __restrict__ ow2, const float* __restrict__ ob0, const float* __restrict__ ob1,
    const float* __restrict__ ob2, u16* __restrict__ w2f, float* __restrict__ w2b)
{
  int t = blockIdx.x*256 + threadIdx.x;      // 9*6*64*32
  if (t < 64) {
    float bv = 0.f;
    if (t < 32)      bv = ob0[t];
    else if (t < 48) bv = ob1[t-32];
    else if (t < 56) bv = ob2[t-48];
    w2b[t] = bv;
  }
  int kk = t & 31; int rest = t >> 5;
  int oc = rest & 63; rest >>= 6;            // rest = tap*6 + c
  int c = rest % NCH2, tap = rest / NCH2;
  int ic = c*32 + kk;
  u16 v = 0;
  if (ic < 176) {
    if (oc < 32)      v = f2bf(ow0[(size_t)oc*1584      + (size_t)ic*9 + tap]);
    else if (oc < 48) v = f2bf(ow1[(size_t)(oc-32)*1584 + (size_t)ic*9 + tap]);
    else if (oc < 56) v = f2bf(ow2[(size_t)(oc-48)*1584 + (size_t)ic*9 + tap]);
  }
  w2f[t] = v;
}

// ---------- mean over N (NHWC bf16 out) + GN group stats (f32) ----------
__global__ __launch_bounds__(320) void k_mean(const float* __restrict__ x, u16* __restrict__ mh, float* __restrict__ gstats)
{
  int plane = blockIdx.x / 135;                    // b*128 + c
  int pix   = (blockIdx.x % 135)*320 + threadIdx.x;
  int b = plane >> 7, c = plane & 127;
  const float* xp = x + ((size_t)(b*896 + c))*HW + pix;   // 896 = N*C
  float s = 0.f;
  #pragma unroll
  for (int nn = 0; nn < 7; ++nn) s += xp[(size_t)nn*5529600];  // stride C*HW
  float mval = s * (1.f/7.f);
  mh[((size_t)(b*HW + pix))*128 + c] = f2bf(mval);
  float s1 = mval, s2 = mval*mval;
  #pragma unroll
  for (int o = 32; o > 0; o >>= 1){ s1 += __shfl_down(s1, o); s2 += __shfl_down(s2, o); }
  __shared__ float r1[5], r2[5];
  int wid = threadIdx.x >> 6, lane = threadIdx.x & 63;
  if (lane == 0){ r1[wid] = s1; r2[wid] = s2; }
  __syncthreads();
  if (threadIdx.x == 0){
    float t1 = r1[0]+r1[1]+r1[2]+r1[3]+r1[4];
    float t2 = r2[0]+r2[1]+r2[2]+r2[3]+r2[4];
    int gi = (b*16 + (c>>3))*2;
    atomicAdd(&gstats[gi],   t1);
    atomicAdd(&gstats[gi+1], t2);
  }
}

// ---------- pass A: group-norm -> lr into lrs[ch 0..128), zeros 176..192), per-pixel norm ----------
__global__ __launch_bounds__(256) void k_passA(const u16* __restrict__ mh, const float* __restrict__ gg,
    const float* __restrict__ gb, const float* __restrict__ gstats, u16* __restrict__ lrs, float* __restrict__ cn)
{
  __shared__ float sg[128], sb[128], smu[32], srs[32];
  int tid = threadIdx.x;
  if (tid < 128){ sg[tid] = gg[tid]; sb[tid] = gb[tid]; }
  else if (tid < 160){
    int i = tid-128;
    float s = gstats[2*i], s2 = gstats[2*i+1];
    float mu = s * (1.f/345600.f);
    float var = s2 * (1.f/345600.f) - mu*mu; if (var < 0.f) var = 0.f;
    smu[i] = mu; srs[i] = rsqrtf(var + 1e-5f);
  }
  __syncthreads();
  int p = blockIdx.x*256 + tid; if (p >= PIX) return;
  int b = p / HW, pix = p - b*HW, h = pix/Ww, w = pix - h*Ww;
  const uint4* src = (const uint4*)(mh + (size_t)p*128);
  u16* dst = lrs + ((size_t)(b*HP + h+1)*WP + (w+1))*ICP2;
  float ss = 0.f;
  #pragma unroll
  for (int t = 0; t < 16; ++t) {
    uint4 v = src[t];
    u32 wds[4] = {v.x, v.y, v.z, v.w};
    u32 ot[4];
    #pragma unroll
    for (int e = 0; e < 4; ++e) {
      int c0 = t*8 + e*2;
      int g0 = b*16 + (c0>>3);
      float a0 = (bflo(wds[e]) - smu[g0])*srs[g0]*sg[c0]   + sb[c0];
      float a1 = (bfhi(wds[e]) - smu[g0])*srs[g0]*sg[c0+1] + sb[c0+1];
      ss += a0*a0 + a1*a1;
      ot[e] = (u32)f2bf(a0) | ((u32)f2bf(a1) << 16);
    }
    ((uint4*)dst)[t] = make_uint4(ot[0], ot[1], ot[2], ot[3]);
  }
  uint4 z = make_uint4(0,0,0,0);
  ((uint4*)dst)[22] = z; ((uint4*)dst)[23] = z;      // channels 176..191
  cn[p] = fmaxf(sqrtf(ss), 1e-8f);
}

// ---------- pass B: 48 dilated cosine sims into lrs[ch 128..176) ----------
__global__ __launch_bounds__(256) void k_passB(u16* __restrict__ lrs, const float* __restrict__ cn)
{
  int p = blockIdx.x*256 + threadIdx.x; if (p >= PIX) return;
  int b = p / HW, pix = p - b*HW, h = pix/Ww, w = pix - h*Ww;
  u16* base = lrs + ((size_t)(b*HP + h+1)*WP + (w+1))*ICP2;
  uint4 own[16];
  #pragma unroll
  for (int t = 0; t < 16; ++t) own[t] = ((const uint4*)base)[t];
  float cnp = cn[p];
  u32 outw[24] __attribute__((aligned(16)));
  int k = 0;
  for (int i = 0; i < 7; ++i)
    for (int j = 0; j < 7; ++j) {
      if (i == 3 && j == 3) continue;
      int hq = h + 2*i - 6, wq = w + 2*j - 6;
      float sim = 0.f;
      if ((unsigned)hq < 120u && (unsigned)wq < 360u) {
        const u16* nb = lrs + ((size_t)(b*HP + hq+1)*WP + (wq+1))*ICP2;
        float dot = 0.f;
        #pragma unroll
        for (int t = 0; t < 16; ++t) {
          uint4 a = own[t]; uint4 c = ((const uint4*)nb)[t];
          dot += bflo(a.x)*bflo(c.x) + bfhi(a.x)*bfhi(c.x);
          dot += bflo(a.y)*bflo(c.y) + bfhi(a.y)*bfhi(c.y);
          dot += bflo(a.z)*bflo(c.z) + bfhi(a.z)*bfhi(c.z);
          dot += bflo(a.w)*bflo(c.w) + bfhi(a.w)*bfhi(c.w);
        }
        sim = dot / (cnp * cn[b*HW + hq*Ww + wq]);
      }
      u32 bv = f2bf(sim);
      if (k & 1) outw[k>>1] |= bv << 16; else outw[k>>1] = bv;
      ++k;
    }
  #pragma unroll
  for (int t = 0; t < 6; ++t) ((uint4*)(base + 128))[t] = ((uint4*)outw)[t];
}

// ---------- pack x (f32 NCHW + coord channels) to padded NHWC bf16 via LDS transpose ----------
__global__ __launch_bounds__(256) void k_pack(const float* __restrict__ x, u16* __restrict__ xh)
{
  __shared__ u16 plds[64*66];
  int bx = blockIdx.x;                 // 0..89
  int wt = bx / 15, ict = bx % 15;
  int h = blockIdx.y, b = blockIdx.z;
  int tid = threadIdx.x;
  int wl = tid & 63, icq = tid >> 6;
  int w = wt*64 + wl;
  bool wok = (w < Ww);
  #pragma unroll
  for (int r = 0; r < 16; ++r) {
    int icl = icq*16 + r;
    int ic = ict*64 + icl;
    u16 v = 0;
    if (wok) {
      if (ic < 896) {
        int nn = ic >> 7, cc = ic & 127;
        v = f2bf(x[((size_t)((b*7 + nn)*128 + cc))*HW + h*Ww + w]);
      } else if (ic == 896) v = f2bf((float)w*(2.f/359.f) - 1.f);
      else if (ic == 897)   v = f2bf((float)h*(2.f/119.f) - 1.f);
    }
    plds[icl*66 + wl] = v;
  }
  __syncthreads();
  #pragma unroll
  for (int rep = 0; rep < 2; ++rep) {
    int unit = tid + rep*256;
    int wr = unit >> 3, seg = unit & 7;
    int wq = wt*64 + wr, icb = ict*64 + seg*8;
    if (wq < Ww && icb < ICP1) {
      u32 pk[4];
      #pragma unroll
      for (int kk = 0; kk < 4; ++kk) {
        u32 lo = plds[(seg*8 + 2*kk    )*66 + wr];
        u32 hi = plds[(seg*8 + 2*kk + 1)*66 + wr];
        pk[kk] = lo | (hi << 16);
      }
      *(uint4*)(xh + ((size_t)(b*HP + h+1)*WP + (wq+1))*ICP1 + icb) = make_uint4(pk[0],pk[1],pk[2],pk[3]);
    }
  }
}

// ---------- implicit-GEMM 3x3 conv, bf16 MFMA 16x16x32 ----------
// block: 2 out rows x 64 w (M=128) x OC. A staged to LDS (swizzled), B read
// coalesced from fragment-ordered weights in L2. bias always f32.
template<int NCHUNK, int OC, int NWM, int NWN, bool RELU, bool OUTF32>
__global__ __launch_bounds__(256) void k_conv(const u16* __restrict__ inb, const u16* __restrict__ wf,
                                              const float* __restrict__ bias, void* __restrict__ outp)
{
  static_assert(NWM*NWN == 4, "4 waves");
  constexpr int ICPAD = NCHUNK*32;
  constexpr int WM = 8/NWM;
  constexpr int WN = (OC/16)/NWN;
  __shared__ __align__(16) u16 alds[4*66*32];      // [row4][wc66][ic32], 16B-unit swizzled
  const int wt = blockIdx.x, h2 = blockIdx.y, b = blockIdx.z;
  const int h0 = h2*2, w0 = wt*64;
  const int tid = threadIdx.x, wid = tid >> 6, lane = tid & 63;
  const int q = lane >> 4, n = lane & 15;
  const int mi = wid / NWN, ni = wid % NWN;

  f32x4 zz = {0.f,0.f,0.f,0.f};
  f32x4 acc[WM][WN];
  #pragma unroll
  for (int a = 0; a < WM; ++a)
    #pragma unroll
    for (int bq = 0; bq < WN; ++bq) acc[a][bq] = zz;

  const size_t pixbase = (size_t)(b*HP + h0)*WP + w0;

  for (int c = 0; c < NCHUNK; ++c) {
    __syncthreads();
    {   // wave `wid` stages input row wid (66 wc x 32 ic, 16B units)
      const int row = wid;
      #pragma unroll
      for (int o = 0; o < 5; ++o) {
        if (o < 4 || lane < 8) {
          int uir = o*64 + lane;                    // unit-in-row 0..263
          int wc = uir >> 2, sw = uir & 3;
          int idx = row*66 + wc;
          int s = sw ^ ((idx + (idx >> 2)) & 3);    // bank-phase swizzle
          const u16* g = inb + (pixbase + (size_t)row*WP + wc)*ICPAD + c*32 + s*8;
          gl_lds16(g, alds + (row*264 + o*64)*8);
        }
      }
    }
    __syncthreads();
    #pragma unroll
    for (int tap = 0; tap < 9; ++tap) {
      const int kh = tap/3, kw = tap%3;
      bf16x8 bfr[WN];
      #pragma unroll
      for (int gn = 0; gn < WN; ++gn) {
        int oc = (ni*WN + gn)*16 + n;
        bfr[gn] = *(const bf16x8*)(wf + (((size_t)tap*NCHUNK + c)*OC + oc)*32 + q*8);
      }
      bf16x8 afr[WM];
      #pragma unroll
      for (int gm = 0; gm < WM; ++gm) {
        int G = mi*WM + gm;
        int idx = ((G>>2) + kh)*66 + (G&3)*16 + n + kw;
        int U = 4*idx + (q ^ ((idx + (idx>>2)) & 3));
        afr[gm] = *(const bf16x8*)(alds + U*8);
      }
      #pragma unroll
      for (int gm = 0; gm < WM; ++gm)
        #pragma unroll
        for (int gn = 0; gn < WN; ++gn)
          acc[gm][gn] = __builtin_amdgcn_mfma_f32_16x16x32_bf16(afr[gm], bfr[gn], acc[gm][gn], 0, 0, 0);
    }
  }
  #pragma unroll
  for (int gn = 0; gn < WN; ++gn) {
    int oc = (ni*WN + gn)*16 + n;
    float bv = bias[oc];
    #pragma unroll
    for (int gm = 0; gm < WM; ++gm) {
      int G = mi*WM + gm;
      #pragma unroll
      for (int r = 0; r < 4; ++r) {
        int p = G*16 + q*4 + r;
        int w = w0 + (p & 63);
        if (w < Ww) {
          int h = h0 + (p >> 6);
          float v = acc[gm][gn][r] + bv;
          if (RELU) v = fmaxf(v, 0.f);
          size_t oi = ((size_t)(b*Hh + h)*Ww + w)*OC + oc;
          if (OUTF32) ((float*)outp)[oi] = v;
          else        ((u16*)outp)[oi]  = f2bf(v);
        }
      }
    }
  }
}

// ---------- deform-sample 3 offset sets + average, NCHW f32 out ----------
__device__ __forceinline__ void samp_add(float* acc, const u16* __restrict__ feat,
                                         int b, int h, int w, float ox, float oy, int c0)
{
  float ix = (float)w + ox, iy = (float)h + oy;
  float x0f = floorf(ix), y0f = floorf(iy);
  float wx = ix - x0f, wy = iy - y0f;
  int x0 = (int)x0f, y0 = (int)y0f;
  int x0c = min(max(x0, 0), 359),   x1c = min(max(x0+1, 0), 359);
  int y0c = min(max(y0, 0), 119),   y1c = min(max(y0+1, 0), 119);
  const u16* fb = feat + (size_t)b*HW*128 + c0;
  uint4 v00 = *(const uint4*)(fb + ((size_t)y0c*Ww + x0c)*128);
  uint4 v01 = *(const uint4*)(fb + ((size_t)y0c*Ww + x1c)*128);
  uint4 v10 = *(const uint4*)(fb + ((size_t)y1c*Ww + x0c)*128);
  uint4 v11 = *(const uint4*)(fb + ((size_t)y1c*Ww + x1c)*128);
  float w00 = (1.f-wx)*(1.f-wy), w01 = wx*(1.f-wy), w10 = (1.f-wx)*wy, w11 = wx*wy;
  u32 a00[4] = {v00.x,v00.y,v00.z,v00.w};
  u32 a01[4] = {v01.x,v01.y,v01.z,v01.w};
  u32 a10[4] = {v10.x,v10.y,v10.z,v10.w};
  u32 a11[4] = {v11.x,v11.y,v11.z,v11.w};
  #pragma unroll
  for (int e = 0; e < 4; ++e) {
    acc[2*e]   += w00*bflo(a00[e]) + w01*bflo(a01[e]) + w10*bflo(a10[e]) + w11*bflo(a11[e]);
    acc[2*e+1] += w00*bfhi(a00[e]) + w01*bfhi(a01[e]) + w10*bfhi(a10[e]) + w11*bfhi(a11[e]);
  }
}

__global__ __launch_bounds__(256) void k_sample(const u16* __restrict__ feat, const float* __restrict__ offs,
                                                float* __restrict__ out)
{
  int lane = threadIdx.x & 63;
  int cc = blockIdx.y*4 + (threadIdx.x >> 6);     // 0..15: 8-channel chunk
  int pix = blockIdx.x*64 + lane;                 // 675*64 = 43200 exact
  int b = blockIdx.z;
  int h = pix/Ww, w = pix - h*Ww;
  const float* ob = offs + ((size_t)b*HW + pix)*64;
  float acc[8] = {0,0,0,0,0,0,0,0};
  samp_add(acc, feat, b, h, w, ob[cc],          ob[16+cc],       cc*8);   // off0: 16 groups
  samp_add(acc, feat, b, h, w, ob[32+(cc>>1)],  ob[40+(cc>>1)],  cc*8);   // off1: 8 groups
  samp_add(acc, feat, b, h, w, ob[48+(cc>>2)],  ob[52+(cc>>2)],  cc*8);   // off2: 4 groups
  #pragma unroll
  for (int e = 0; e < 8; ++e)
    out[((size_t)(b*128 + cc*8 + e))*HW + pix] = acc[e] * (1.f/3.f);
}

// ---------- launch ----------
extern "C" void kernel_launch(void* const* d_in, const int* in_sizes, int n_in,
                              void* d_out, int out_size, void* d_ws, size_t ws_size,
                              hipStream_t stream)
{
  (void)in_sizes; (void)n_in; (void)out_size; (void)ws_size;
  const float* x      = (const float*)d_in[0];
  const float* conv_w = (const float*)d_in[1];
  const float* conv_b = (const float*)d_in[2];
  const float* gn_g   = (const float*)d_in[3];
  const float* gn_b   = (const float*)d_in[4];
  const float* off_w  = (const float*)d_in[5];
  const float* off_b  = (const float*)d_in[6];
  const float* off1_w = (const float*)d_in[7];
  const float* off1_b = (const float*)d_in[8];
  const float* off2_w = (const float*)d_in[9];
  const float* off2_b = (const float*)d_in[10];
  float* out = (float*)d_out;

  char* ws = (char*)d_ws;
  u16*   xh   = (u16*)(ws + OFF_XH);
  u16*   lrs  = (u16*)(ws + OFF_LRS);
  u16*   mh   = (u16*)(ws + OFF_FEAT);   // aliases feat (mh consumed before conv writes feat)
  u16*   feat = mh;
  float* offs = (float*)(ws + OFF_XH);   // aliases xh (xh consumed before offset conv writes)
  u16*   w1f  = (u16*)(ws + OFF_W1F);
  u16*   w2f  = (u16*)(ws + OFF_W2F);
  float* w2b  = (float*)(ws + OFF_W2B);
  float* cn   = (float*)(ws + OFF_CN);
  float* gst  = (float*)(ws + OFF_GST);

  k_init   <<<dim3(1055),        dim3(256), 0, stream>>>(xh, lrs, gst);
  k_prep_w1<<<dim3(4176),        dim3(256), 0, stream>>>(conv_w, w1f);
  k_prep_w2<<<dim3(432),         dim3(256), 0, stream>>>(off_w, off1_w, off2_w, off_b, off1_b, off2_b, w2f, w2b);
  k_mean   <<<dim3(34560),       dim3(320), 0, stream>>>(x, mh, gst);
  k_passA  <<<dim3(338),         dim3(256), 0, stream>>>(mh, gn_g, gn_b, gst, lrs, cn);
  k_passB  <<<dim3(338),         dim3(256), 0, stream>>>(lrs, cn);
  k_pack   <<<dim3(90,120,2),    dim3(256), 0, stream>>>(x, xh);
  k_conv<NCH1,128,2,2,true ,false><<<dim3(6,60,2), dim3(256), 0, stream>>>(xh,  w1f, conv_b, feat);
  k_conv<NCH2, 64,4,1,false,true ><<<dim3(6,60,2), dim3(256), 0, stream>>>(lrs, w2f, w2b,   offs);
  k_sample <<<dim3(675,4,2),     dim3(256), 0, stream>>>(feat, offs, out);
}

// Round 3
// 1544.983 us; speedup vs baseline: 1.1201x; 1.1201x over previous
//
#include <hip/hip_runtime.h>

typedef unsigned short u16;
typedef unsigned int   u32;
typedef short bf16x8 __attribute__((ext_vector_type(8)));
typedef float f32x4  __attribute__((ext_vector_type(4)));

// ---------- geometry ----------
#define Bn   2
#define Nn   7
#define Cc   128
#define Hh   120
#define Ww   360
#define HW   43200          // Hh*Ww
#define PIX  86400          // Bn*HW
#define HP   122            // padded H (h index +1)
#define WP   362            // padded W (w index +1)
#define ICP1 928            // 29*32 (898 real + pad)
#define NCH1 29
#define ICP2 192            // 6*32  (176 real + pad)
#define NCH2 6

// ---------- ws layout (bytes, 256-aligned) ----------
constexpr size_t AL(size_t x){ return (x + 255) & ~size_t(255); }
constexpr size_t XH_BYTES  = (size_t)Bn*HP*WP*ICP1*2;      // ~163.9 MB
constexpr size_t LRS_BYTES = (size_t)Bn*HP*WP*ICP2*2;      // ~33.9 MB
constexpr size_t OFF_XH  = 0;
constexpr size_t OFF_LRS = AL(OFF_XH + XH_BYTES + 65536);     // slack for conv A-tile overrun
constexpr size_t OFF_FEAT= AL(OFF_LRS + LRS_BYTES + 65536);   // feat aliases mh (mh dead before conv)
constexpr size_t OFF_W1F = AL(OFF_FEAT + (size_t)PIX*128*2);
constexpr size_t OFF_W2F = AL(OFF_W1F + (size_t)9*NCH1*128*32*2);
constexpr size_t OFF_W2B = AL(OFF_W2F + (size_t)9*NCH2*64*32*2);
constexpr size_t OFF_CN  = AL(OFF_W2B + 256);
constexpr size_t OFF_GST = AL(OFF_CN + (size_t)PIX*4);
// offsets buffer (f32, PIX*64*4 = 22.1MB) aliases xh (xh dead after main conv)

// ---------- helpers ----------
__device__ __forceinline__ float bf2f(u16 h){ union{u32 u; float f;} c; c.u = ((u32)h)<<16; return c.f; }
__device__ __forceinline__ u16 f2bf(float f){
  union{float f; u32 u;} c; c.f = f;
  u32 r = (c.u + 0x7FFFu + ((c.u>>16)&1u)) >> 16;
  return (u16)r;
}
__device__ __forceinline__ float bflo(u32 a){ union{u32 u; float f;} c; c.u = a<<16;          return c.f; }
__device__ __forceinline__ float bfhi(u32 a){ union{u32 u; float f;} c; c.u = a & 0xffff0000u; return c.f; }

__device__ __forceinline__ void gl_lds16(const u16* g, u16* l){
  __builtin_amdgcn_global_load_lds((const __attribute__((address_space(1))) void*)g,
                                   (__attribute__((address_space(3))) void*)l, 16, 0, 0);
}

// ---------- init: zero gstats + spatial pads of xh / lrs ----------
__global__ __launch_bounds__(256) void k_init(u16* __restrict__ xh, u16* __restrict__ lrs, float* __restrict__ gstats)
{
  int t = blockIdx.x*256 + threadIdx.x;
  if (t < 64) gstats[t] = 0.f;
  t -= 64;
  if (t < 0 || t >= 2*964*140) return;
  int b = t / (964*140); int r = t - b*(964*140);
  int i = r / 140, chunk = r - i*140;
  int hp, wp;
  if (i < 362)      { hp = 0;   wp = i; }
  else if (i < 724) { hp = 121; wp = i-362; }
  else { int j = i-724; hp = 1 + (j>>1); wp = (j&1) ? 361 : 0; }
  size_t pixel = (size_t)(b*HP + hp)*WP + wp;
  uint4 z = make_uint4(0,0,0,0);
  if (chunk < 116) ((uint4*)(xh  + pixel*ICP1))[chunk]      = z;
  else             ((uint4*)(lrs + pixel*ICP2))[chunk-116]  = z;
}

// ---------- weight prep: MFMA-fragment-ordered  [tap][chunk][oc][32] ----------
__global__ __launch_bounds__(256) void k_prep_w1(const float* __restrict__ cw, u16* __restrict__ w1f)
{
  int t = blockIdx.x*256 + threadIdx.x;      // 9*29*128*32
  int kk = t & 31; int rest = t >> 5;
  int oc = rest & 127; rest >>= 7;           // rest = tap*29 + c
  int c = rest % NCH1, tap = rest / NCH1;
  int ic = c*32 + kk;
  u16 v = 0;
  if (ic < 898) v = f2bf(cw[(size_t)oc*8082 + (size_t)ic*9 + tap]);
  w1f[t] = v;
}

__global__ __launch_bounds__(256) void k_prep_w2(const float* __restrict__ ow0, const float* __restrict__ ow1,
    const float* __restrict__ ow2, const float* __restrict__ ob0, const float* __restrict__ ob1,
    const float* __restrict__ ob2, u16* __restrict__ w2f, float* __restrict__ w2b)
{
  int t = blockIdx.x*256 + threadIdx.x;      // 9*6*64*32
  if (t < 64) {
    float bv = 0.f;
    if (t < 32)      bv = ob0[t];
    else if (t < 48) bv = ob1[t-32];
    else if (t < 56) bv = ob2[t-48];
    w2b[t] = bv;
  }
  int kk = t & 31; int rest = t >> 5;
  int oc = rest & 63; rest >>= 6;            // rest = tap*6 + c
  int c = rest % NCH2, tap = rest / NCH2;
  int ic = c*32 + kk;
  u16 v = 0;
  if (ic < 176) {
    if (oc < 32)      v = f2bf(ow0[(size_t)oc*1584      + (size_t)ic*9 + tap]);
    else if (oc < 48) v = f2bf(ow1[(size_t)(oc-32)*1584 + (size_t)ic*9 + tap]);
    else if (oc < 56) v = f2bf(ow2[(size_t)(oc-48)*1584 + (size_t)ic*9 + tap]);
  }
  w2f[t] = v;
}

// ---------- pack x (f32 NCHW + coord channels) to padded NHWC bf16 via LDS transpose ----------
__global__ __launch_bounds__(256) void k_pack(const float* __restrict__ x, u16* __restrict__ xh)
{
  __shared__ u16 plds[64*66];
  int bx = blockIdx.x;                 // 0..89
  int wt = bx / 15, ict = bx % 15;
  int h = blockIdx.y, b = blockIdx.z;
  int tid = threadIdx.x;
  int wl = tid & 63, icq = tid >> 6;
  int w = wt*64 + wl;
  bool wok = (w < Ww);
  #pragma unroll
  for (int r = 0; r < 16; ++r) {
    int icl = icq*16 + r;
    int ic = ict*64 + icl;
    u16 v = 0;
    if (wok) {
      if (ic < 896) {
        int nn = ic >> 7, cc = ic & 127;
        v = f2bf(x[((size_t)((b*7 + nn)*128 + cc))*HW + h*Ww + w]);
      } else if (ic == 896) v = f2bf((float)w*(2.f/359.f) - 1.f);
      else if (ic == 897)   v = f2bf((float)h*(2.f/119.f) - 1.f);
    }
    plds[icl*66 + wl] = v;
  }
  __syncthreads();
  #pragma unroll
  for (int rep = 0; rep < 2; ++rep) {
    int unit = tid + rep*256;
    int wr = unit >> 3, seg = unit & 7;
    int wq = wt*64 + wr, icb = ict*64 + seg*8;
    if (wq < Ww && icb < ICP1) {
      u32 pk[4];
      #pragma unroll
      for (int kk = 0; kk < 4; ++kk) {
        u32 lo = plds[(seg*8 + 2*kk    )*66 + wr];
        u32 hi = plds[(seg*8 + 2*kk + 1)*66 + wr];
        pk[kk] = lo | (hi << 16);
      }
      *(uint4*)(xh + ((size_t)(b*HP + h+1)*WP + (wq+1))*ICP1 + icb) = make_uint4(pk[0],pk[1],pk[2],pk[3]);
    }
  }
}

// ---------- mean over N from NHWC xh (contiguous records) + GN group stats ----------
// one thread per pixel: read 7*128ch bf16 (16B vec loads), mean in f32,
// write 256B contiguous mh record, wave-reduce GN sums + atomics.
__global__ __launch_bounds__(256) void k_meanB(const u16* __restrict__ xh, u16* __restrict__ mh,
                                               float* __restrict__ gstats)
{
  int b = blockIdx.y;
  int p = blockIdx.x*256 + threadIdx.x;          // grid.x = 169 -> 43264 >= HW
  bool ok = (p < HW);
  int pp = ok ? p : 0;
  int h = pp / Ww, w = pp - h*Ww;
  const u16* rec = xh + ((size_t)(b*HP + h+1)*WP + (w+1))*ICP1;
  u16* dst = mh + ((size_t)b*HW + pp)*128;
  int lane = threadIdx.x & 63;
  #pragma unroll
  for (int cq = 0; cq < 4; ++cq) {
    float s[32];
    #pragma unroll
    for (int i = 0; i < 32; ++i) s[i] = 0.f;
    #pragma unroll
    for (int nn = 0; nn < 7; ++nn) {
      const uint4* q4 = (const uint4*)(rec + nn*128 + cq*32);
      #pragma unroll
      for (int t = 0; t < 4; ++t) {
        uint4 v = ok ? q4[t] : make_uint4(0,0,0,0);
        u32 wd[4] = {v.x, v.y, v.z, v.w};
        #pragma unroll
        for (int e = 0; e < 4; ++e) { s[t*8+e*2] += bflo(wd[e]); s[t*8+e*2+1] += bfhi(wd[e]); }
      }
    }
    float g1[4] = {0,0,0,0}, g2[4] = {0,0,0,0};
    #pragma unroll
    for (int i = 0; i < 32; ++i) {
      float mval = s[i] * (1.f/7.f);
      s[i] = mval;
      int g = i >> 3;
      g1[g] += mval; g2[g] += mval*mval;
    }
    if (ok) {
      u32 ow[16];
      #pragma unroll
      for (int i = 0; i < 16; ++i) ow[i] = (u32)f2bf(s[2*i]) | ((u32)f2bf(s[2*i+1]) << 16);
      #pragma unroll
      for (int t = 0; t < 4; ++t)
        ((uint4*)(dst + cq*32))[t] = make_uint4(ow[4*t], ow[4*t+1], ow[4*t+2], ow[4*t+3]);
    }
    #pragma unroll
    for (int g = 0; g < 4; ++g) {
      float a = g1[g], bb = g2[g];
      #pragma unroll
      for (int o = 32; o > 0; o >>= 1) { a += __shfl_down(a, o); bb += __shfl_down(bb, o); }
      if (lane == 0) {
        int gi = (b*16 + cq*4 + g)*2;
        atomicAdd(&gstats[gi],   a);
        atomicAdd(&gstats[gi+1], bb);
      }
    }
  }
}

// ---------- pass A: group-norm -> lr into lrs[ch 0..128), zeros 176..192), per-pixel norm ----------
__global__ __launch_bounds__(256) void k_passA(const u16* __restrict__ mh, const float* __restrict__ gg,
    const float* __restrict__ gb, const float* __restrict__ gstats, u16* __restrict__ lrs, float* __restrict__ cn)
{
  __shared__ float sg[128], sb[128], smu[32], srs[32];
  int tid = threadIdx.x;
  if (tid < 128){ sg[tid] = gg[tid]; sb[tid] = gb[tid]; }
  else if (tid < 160){
    int i = tid-128;
    float s = gstats[2*i], s2 = gstats[2*i+1];
    float mu = s * (1.f/345600.f);
    float var = s2 * (1.f/345600.f) - mu*mu; if (var < 0.f) var = 0.f;
    smu[i] = mu; srs[i] = rsqrtf(var + 1e-5f);
  }
  __syncthreads();
  int p = blockIdx.x*256 + tid; if (p >= PIX) return;
  int b = p / HW, pix = p - b*HW, h = pix/Ww, w = pix - h*Ww;
  const uint4* src = (const uint4*)(mh + (size_t)p*128);
  u16* dst = lrs + ((size_t)(b*HP + h+1)*WP + (w+1))*ICP2;
  float ss = 0.f;
  #pragma unroll
  for (int t = 0; t < 16; ++t) {
    uint4 v = src[t];
    u32 wds[4] = {v.x, v.y, v.z, v.w};
    u32 ot[4];
    #pragma unroll
    for (int e = 0; e < 4; ++e) {
      int c0 = t*8 + e*2;
      int g0 = b*16 + (c0>>3);
      float a0 = (bflo(wds[e]) - smu[g0])*srs[g0]*sg[c0]   + sb[c0];
      float a1 = (bfhi(wds[e]) - smu[g0])*srs[g0]*sg[c0+1] + sb[c0+1];
      ss += a0*a0 + a1*a1;
      ot[e] = (u32)f2bf(a0) | ((u32)f2bf(a1) << 16);
    }
    ((uint4*)dst)[t] = make_uint4(ot[0], ot[1], ot[2], ot[3]);
  }
  uint4 z = make_uint4(0,0,0,0);
  ((uint4*)dst)[22] = z; ((uint4*)dst)[23] = z;      // channels 176..191
  cn[p] = fmaxf(sqrtf(ss), 1e-8f);
}

// ---------- pass B: 48 dilated cosine sims into lrs[ch 128..176) ----------
__global__ __launch_bounds__(256) void k_passB(u16* __restrict__ lrs, const float* __restrict__ cn)
{
  int p = blockIdx.x*256 + threadIdx.x; if (p >= PIX) return;
  int b = p / HW, pix = p - b*HW, h = pix/Ww, w = pix - h*Ww;
  u16* base = lrs + ((size_t)(b*HP + h+1)*WP + (w+1))*ICP2;
  uint4 own[16];
  #pragma unroll
  for (int t = 0; t < 16; ++t) own[t] = ((const uint4*)base)[t];
  float cnp = cn[p];
  u32 outw[24] __attribute__((aligned(16)));
  int k = 0;
  for (int i = 0; i < 7; ++i)
    for (int j = 0; j < 7; ++j) {
      if (i == 3 && j == 3) continue;
      int hq = h + 2*i - 6, wq = w + 2*j - 6;
      float sim = 0.f;
      if ((unsigned)hq < 120u && (unsigned)wq < 360u) {
        const u16* nb = lrs + ((size_t)(b*HP + hq+1)*WP + (wq+1))*ICP2;
        float dot = 0.f;
        #pragma unroll
        for (int t = 0; t < 16; ++t) {
          uint4 a = own[t]; uint4 c = ((const uint4*)nb)[t];
          dot += bflo(a.x)*bflo(c.x) + bfhi(a.x)*bfhi(c.x);
          dot += bflo(a.y)*bflo(c.y) + bfhi(a.y)*bfhi(c.y);
          dot += bflo(a.z)*bflo(c.z) + bfhi(a.z)*bfhi(c.z);
          dot += bflo(a.w)*bflo(c.w) + bfhi(a.w)*bfhi(c.w);
        }
        sim = dot / (cnp * cn[b*HW + hq*Ww + wq]);
      }
      u32 bv = f2bf(sim);
      if (k & 1) outw[k>>1] |= bv << 16; else outw[k>>1] = bv;
      ++k;
    }
  #pragma unroll
  for (int t = 0; t < 6; ++t) ((uint4*)(base + 128))[t] = ((uint4*)outw)[t];
}

// ---------- implicit-GEMM 3x3 conv, bf16 MFMA 16x16x32 ----------
template<int NCHUNK, int OC, int NWM, int NWN, bool RELU, bool OUTF32>
__global__ __launch_bounds__(256) void k_conv(const u16* __restrict__ inb, const u16* __restrict__ wf,
                                              const float* __restrict__ bias, void* __restrict__ outp)
{
  static_assert(NWM*NWN == 4, "4 waves");
  constexpr int ICPAD = NCHUNK*32;
  constexpr int WM = 8/NWM;
  constexpr int WN = (OC/16)/NWN;
  __shared__ __align__(16) u16 alds[4*66*32];      // [row4][wc66][ic32], 16B-unit swizzled
  const int wt = blockIdx.x, h2 = blockIdx.y, b = blockIdx.z;
  const int h0 = h2*2, w0 = wt*64;
  const int tid = threadIdx.x, wid = tid >> 6, lane = tid & 63;
  const int q = lane >> 4, n = lane & 15;
  const int mi = wid / NWN, ni = wid % NWN;

  f32x4 zz = {0.f,0.f,0.f,0.f};
  f32x4 acc[WM][WN];
  #pragma unroll
  for (int a = 0; a < WM; ++a)
    #pragma unroll
    for (int bq = 0; bq < WN; ++bq) acc[a][bq] = zz;

  const size_t pixbase = (size_t)(b*HP + h0)*WP + w0;

  for (int c = 0; c < NCHUNK; ++c) {
    __syncthreads();
    {   // wave `wid` stages input row wid (66 wc x 32 ic, 16B units)
      const int row = wid;
      #pragma unroll
      for (int o = 0; o < 5; ++o) {
        if (o < 4 || lane < 8) {
          int uir = o*64 + lane;                    // unit-in-row 0..263
          int wc = uir >> 2, sw = uir & 3;
          int idx = row*66 + wc;
          int s = sw ^ ((idx + (idx >> 2)) & 3);    // bank-phase swizzle
          const u16* g = inb + (pixbase + (size_t)row*WP + wc)*ICPAD + c*32 + s*8;
          gl_lds16(g, alds + (row*264 + o*64)*8);
        }
      }
    }
    __syncthreads();
    #pragma unroll
    for (int tap = 0; tap < 9; ++tap) {
      const int kh = tap/3, kw = tap%3;
      bf16x8 bfr[WN];
      #pragma unroll
      for (int gn = 0; gn < WN; ++gn) {
        int oc = (ni*WN + gn)*16 + n;
        bfr[gn] = *(const bf16x8*)(wf + (((size_t)tap*NCHUNK + c)*OC + oc)*32 + q*8);
      }
      bf16x8 afr[WM];
      #pragma unroll
      for (int gm = 0; gm < WM; ++gm) {
        int G = mi*WM + gm;
        int idx = ((G>>2) + kh)*66 + (G&3)*16 + n + kw;
        int U = 4*idx + (q ^ ((idx + (idx>>2)) & 3));
        afr[gm] = *(const bf16x8*)(alds + U*8);
      }
      #pragma unroll
      for (int gm = 0; gm < WM; ++gm)
        #pragma unroll
        for (int gn = 0; gn < WN; ++gn)
          acc[gm][gn] = __builtin_amdgcn_mfma_f32_16x16x32_bf16(afr[gm], bfr[gn], acc[gm][gn], 0, 0, 0);
    }
  }
  #pragma unroll
  for (int gn = 0; gn < WN; ++gn) {
    int oc = (ni*WN + gn)*16 + n;
    float bv = bias[oc];
    #pragma unroll
    for (int gm = 0; gm < WM; ++gm) {
      int G = mi*WM + gm;
      #pragma unroll
      for (int r = 0; r < 4; ++r) {
        int p = G*16 + q*4 + r;
        int w = w0 + (p & 63);
        if (w < Ww) {
          int h = h0 + (p >> 6);
          float v = acc[gm][gn][r] + bv;
          if (RELU) v = fmaxf(v, 0.f);
          size_t oi = ((size_t)(b*Hh + h)*Ww + w)*OC + oc;
          if (OUTF32) ((float*)outp)[oi] = v;
          else        ((u16*)outp)[oi]  = f2bf(v);
        }
      }
    }
  }
}

// ---------- deform-sample 3 offset sets + average, NCHW f32 out ----------
__device__ __forceinline__ void samp_add(float* acc, const u16* __restrict__ feat,
                                         int b, int h, int w, float ox, float oy, int c0)
{
  float ix = (float)w + ox, iy = (float)h + oy;
  float x0f = floorf(ix), y0f = floorf(iy);
  float wx = ix - x0f, wy = iy - y0f;
  int x0 = (int)x0f, y0 = (int)y0f;
  int x0c = min(max(x0, 0), 359),   x1c = min(max(x0+1, 0), 359);
  int y0c = min(max(y0, 0), 119),   y1c = min(max(y0+1, 0), 119);
  const u16* fb = feat + (size_t)b*HW*128 + c0;
  uint4 v00 = *(const uint4*)(fb + ((size_t)y0c*Ww + x0c)*128);
  uint4 v01 = *(const uint4*)(fb + ((size_t)y0c*Ww + x1c)*128);
  uint4 v10 = *(const uint4*)(fb + ((size_t)y1c*Ww + x0c)*128);
  uint4 v11 = *(const uint4*)(fb + ((size_t)y1c*Ww + x1c)*128);
  float w00 = (1.f-wx)*(1.f-wy), w01 = wx*(1.f-wy), w10 = (1.f-wx)*wy, w11 = wx*wy;
  u32 a00[4] = {v00.x,v00.y,v00.z,v00.w};
  u32 a01[4] = {v01.x,v01.y,v01.z,v01.w};
  u32 a10[4] = {v10.x,v10.y,v10.z,v10.w};
  u32 a11[4] = {v11.x,v11.y,v11.z,v11.w};
  #pragma unroll
  for (int e = 0; e < 4; ++e) {
    acc[2*e]   += w00*bflo(a00[e]) + w01*bflo(a01[e]) + w10*bflo(a10[e]) + w11*bflo(a11[e]);
    acc[2*e+1] += w00*bfhi(a00[e]) + w01*bfhi(a01[e]) + w10*bfhi(a10[e]) + w11*bfhi(a11[e]);
  }
}

__global__ __launch_bounds__(256) void k_sample(const u16* __restrict__ feat, const float* __restrict__ offs,
                                                float* __restrict__ out)
{
  int lane = threadIdx.x & 63;
  int cc = blockIdx.y*4 + (threadIdx.x >> 6);     // 0..15: 8-channel chunk
  int pix = blockIdx.x*64 + lane;                 // 675*64 = 43200 exact
  int b = blockIdx.z;
  int h = pix/Ww, w = pix - h*Ww;
  const float* ob = offs + ((size_t)b*HW + pix)*64;
  float acc[8] = {0,0,0,0,0,0,0,0};
  samp_add(acc, feat, b, h, w, ob[cc],          ob[16+cc],       cc*8);   // off0: 16 groups
  samp_add(acc, feat, b, h, w, ob[32+(cc>>1)],  ob[40+(cc>>1)],  cc*8);   // off1: 8 groups
  samp_add(acc, feat, b, h, w, ob[48+(cc>>2)],  ob[52+(cc>>2)],  cc*8);   // off2: 4 groups
  #pragma unroll
  for (int e = 0; e < 8; ++e)
    out[((size_t)(b*128 + cc*8 + e))*HW + pix] = acc[e] * (1.f/3.f);
}

// ---------- launch ----------
extern "C" void kernel_launch(void* const* d_in, const int* in_sizes, int n_in,
                              void* d_out, int out_size, void* d_ws, size_t ws_size,
                              hipStream_t stream)
{
  (void)in_sizes; (void)n_in; (void)out_size; (void)ws_size;
  const float* x      = (const float*)d_in[0];
  const float* conv_w = (const float*)d_in[1];
  const float* conv_b = (const float*)d_in[2];
  const float* gn_g   = (const float*)d_in[3];
  const float* gn_b   = (const float*)d_in[4];
  const float* off_w  = (const float*)d_in[5];
  const float* off_b  = (const float*)d_in[6];
  const float* off1_w = (const float*)d_in[7];
  const float* off1_b = (const float*)d_in[8];
  const float* off2_w = (const float*)d_in[9];
  const float* off2_b = (const float*)d_in[10];
  float* out = (float*)d_out;

  char* ws = (char*)d_ws;
  u16*   xh   = (u16*)(ws + OFF_XH);
  u16*   lrs  = (u16*)(ws + OFF_LRS);
  u16*   mh   = (u16*)(ws + OFF_FEAT);   // aliases feat (mh consumed in passA before conv writes feat)
  u16*   feat = mh;
  float* offs = (float*)(ws + OFF_XH);   // aliases xh (xh consumed by conv1 before conv2 writes offs)
  u16*   w1f  = (u16*)(ws + OFF_W1F);
  u16*   w2f  = (u16*)(ws + OFF_W2F);
  float* w2b  = (float*)(ws + OFF_W2B);
  float* cn   = (float*)(ws + OFF_CN);
  float* gst  = (float*)(ws + OFF_GST);

  k_init   <<<dim3(1055),        dim3(256), 0, stream>>>(xh, lrs, gst);
  k_prep_w1<<<dim3(4176),        dim3(256), 0, stream>>>(conv_w, w1f);
  k_prep_w2<<<dim3(432),         dim3(256), 0, stream>>>(off_w, off1_w, off2_w, off_b, off1_b, off2_b, w2f, w2b);
  k_pack   <<<dim3(90,120,2),    dim3(256), 0, stream>>>(x, xh);
  k_meanB  <<<dim3(169,2),       dim3(256), 0, stream>>>(xh, mh, gst);
  k_passA  <<<dim3(338),         dim3(256), 0, stream>>>(mh, gn_g, gn_b, gst, lrs, cn);
  k_passB  <<<dim3(338),         dim3(256), 0, stream>>>(lrs, cn);
  k_conv<NCH1,128,2,2,true ,false><<<dim3(6,60,2), dim3(256), 0, stream>>>(xh,  w1f, conv_b, feat);
  k_conv<NCH2, 64,4,1,false,true ><<<dim3(6,60,2), dim3(256), 0, stream>>>(lrs, w2f, w2b,   offs);
  k_sample <<<dim3(675,4,2),     dim3(256), 0, stream>>>(feat, offs, out);
}

// Round 4
// 1419.910 us; speedup vs baseline: 1.2187x; 1.0881x over previous
//
#include <hip/hip_runtime.h>

typedef unsigned short u16;
typedef unsigned int   u32;
typedef short bf16x8 __attribute__((ext_vector_type(8)));
typedef float f32x4  __attribute__((ext_vector_type(4)));

// ---------- geometry ----------
#define Bn   2
#define Nn   7
#define Cc   128
#define Hh   120
#define Ww   360
#define HW   43200          // Hh*Ww
#define PIX  86400          // Bn*HW
#define HP   122            // padded H (h index +1)
#define WP   362            // padded W (w index +1)
#define ICP1 928            // 29*32 (898 real + pad)
#define ICP2 192            // 6*32  (176 real + pad)

// ---------- ws layout (bytes, 256-aligned) ----------
constexpr size_t AL(size_t x){ return (x + 255) & ~size_t(255); }
constexpr size_t XH_BYTES  = (size_t)Bn*HP*WP*ICP1*2;      // ~163.9 MB
constexpr size_t LRS_BYTES = (size_t)Bn*HP*WP*ICP2*2;      // ~33.9 MB
constexpr size_t OFF_XH  = 0;
constexpr size_t OFF_LRS = AL(OFF_XH + XH_BYTES + 65536);     // slack for conv A-tile overrun
constexpr size_t OFF_FEAT= AL(OFF_LRS + LRS_BYTES + 65536);   // feat aliases mh (mh dead before conv)
constexpr size_t OFF_W1F = AL(OFF_FEAT + (size_t)PIX*128*2);
constexpr size_t OFF_W2F = AL(OFF_W1F + (size_t)9*30*128*32*2);   // 30 chunks (29 real + zero pad)
constexpr size_t OFF_W2B = AL(OFF_W2F + (size_t)9*6*64*32*2);
constexpr size_t OFF_CN  = AL(OFF_W2B + 256);
constexpr size_t OFF_GST = AL(OFF_CN + (size_t)PIX*4);
// offsets buffer (f32, PIX*64*4 = 22.1MB) aliases xh (xh dead after main conv)

// ---------- helpers ----------
__device__ __forceinline__ float bf2f(u16 h){ union{u32 u; float f;} c; c.u = ((u32)h)<<16; return c.f; }
__device__ __forceinline__ u16 f2bf(float f){
  union{float f; u32 u;} c; c.f = f;
  u32 r = (c.u + 0x7FFFu + ((c.u>>16)&1u)) >> 16;
  return (u16)r;
}
__device__ __forceinline__ float bflo(u32 a){ union{u32 u; float f;} c; c.u = a<<16;          return c.f; }
__device__ __forceinline__ float bfhi(u32 a){ union{u32 u; float f;} c; c.u = a & 0xffff0000u; return c.f; }

__device__ __forceinline__ void gl_lds16(const u16* g, u16* l){
  __builtin_amdgcn_global_load_lds((const __attribute__((address_space(1))) void*)g,
                                   (__attribute__((address_space(3))) void*)l, 16, 0, 0);
}

// ---------- init: zero gstats + spatial pads of xh / lrs ----------
__global__ __launch_bounds__(256) void k_init(u16* __restrict__ xh, u16* __restrict__ lrs, float* __restrict__ gstats)
{
  int t = blockIdx.x*256 + threadIdx.x;
  if (t < 64) gstats[t] = 0.f;
  t -= 64;
  if (t < 0 || t >= 2*964*140) return;
  int b = t / (964*140); int r = t - b*(964*140);
  int i = r / 140, chunk = r - i*140;
  int hp, wp;
  if (i < 362)      { hp = 0;   wp = i; }
  else if (i < 724) { hp = 121; wp = i-362; }
  else { int j = i-724; hp = 1 + (j>>1); wp = (j&1) ? 361 : 0; }
  size_t pixel = (size_t)(b*HP + hp)*WP + wp;
  uint4 z = make_uint4(0,0,0,0);
  if (chunk < 116) ((uint4*)(xh  + pixel*ICP1))[chunk]      = z;
  else             ((uint4*)(lrs + pixel*ICP2))[chunk-116]  = z;
}

// ---------- weight prep: MFMA-fragment-ordered  [tap][chunk(30)][oc][32] ----------
// chunk 28 = coords + pad, chunk 29 = all-zero (pairs with garbage A reads in BK=64 tail)
__global__ __launch_bounds__(256) void k_prep_w1(const float* __restrict__ cw, u16* __restrict__ w1f)
{
  int t = blockIdx.x*256 + threadIdx.x;      // 9*30*128*32
  int kk = t & 31; int rest = t >> 5;
  int oc = rest & 127; rest >>= 7;           // rest = tap*30 + c
  int c = rest % 30, tap = rest / 30;
  int ic = c*32 + kk;
  u16 v = 0;
  if (ic < 898) v = f2bf(cw[(size_t)oc*8082 + (size_t)ic*9 + tap]);
  w1f[t] = v;
}

__global__ __launch_bounds__(256) void k_prep_w2(const float* __restrict__ ow0, const float* __restrict__ ow1,
    const float* __restrict__ ow2, const float* __restrict__ ob0, const float* __restrict__ ob1,
    const float* __restrict__ ob2, u16* __restrict__ w2f, float* __restrict__ w2b)
{
  int t = blockIdx.x*256 + threadIdx.x;      // 9*6*64*32
  if (t < 64) {
    float bv = 0.f;
    if (t < 32)      bv = ob0[t];
    else if (t < 48) bv = ob1[t-32];
    else if (t < 56) bv = ob2[t-48];
    w2b[t] = bv;
  }
  int kk = t & 31; int rest = t >> 5;
  int oc = rest & 63; rest >>= 6;            // rest = tap*6 + c
  int c = rest % 6, tap = rest / 6;
  int ic = c*32 + kk;
  u16 v = 0;
  if (ic < 176) {
    if (oc < 32)      v = f2bf(ow0[(size_t)oc*1584      + (size_t)ic*9 + tap]);
    else if (oc < 48) v = f2bf(ow1[(size_t)(oc-32)*1584 + (size_t)ic*9 + tap]);
    else if (oc < 56) v = f2bf(ow2[(size_t)(oc-48)*1584 + (size_t)ic*9 + tap]);
  }
  w2f[t] = v;
}

// ---------- fused pack + mean + GN stats ----------
// block = 64 w-pixels x 4 warps; warp handles channel chunks j = warp + 4k.
// Chunks j<28: j = nn*4 + warp -> cc quarter = warp (constant per warp), so
// each warp accumulates the N-mean of its 32 channels for its 64 pixels.
__global__ __launch_bounds__(256) void k_packmean(const float* __restrict__ x, u16* __restrict__ xh,
                                                  u16* __restrict__ mh, float* __restrict__ gstats)
{
  int wt = blockIdx.x, h = blockIdx.y, b = blockIdx.z;
  int lane = threadIdx.x & 63, warp = threadIdx.x >> 6;
  int w = wt*64 + lane;
  bool ok = (w < Ww);
  int wcl = ok ? w : (Ww-1);
  u16* rec = xh + ((size_t)(b*HP + h+1)*WP + (wcl+1))*ICP1;
  const float* xb = x + (size_t)b*7*128*HW + (size_t)h*Ww + wcl;
  float msum[32];
  #pragma unroll
  for (int i = 0; i < 32; ++i) msum[i] = 0.f;

  for (int j = warp; j < 29; j += 4) {
    u32 ow[16];
    if (j < 28) {
      int nn = j >> 2;                                  // j = nn*4 + warp
      const float* src = xb + (size_t)(nn*128 + warp*32)*HW;
      float v[32];
      #pragma unroll
      for (int k = 0; k < 32; ++k) v[k] = ok ? src[(size_t)k*HW] : 0.f;
      #pragma unroll
      for (int k = 0; k < 32; ++k) msum[k] += v[k];
      #pragma unroll
      for (int i = 0; i < 16; ++i) ow[i] = (u32)f2bf(v[2*i]) | ((u32)f2bf(v[2*i+1]) << 16);
    } else {                                            // j == 28: coords + zero pad
      #pragma unroll
      for (int i = 0; i < 16; ++i) ow[i] = 0;
      ow[0] = (u32)f2bf((float)w*(2.f/359.f) - 1.f) | ((u32)f2bf((float)h*(2.f/119.f) - 1.f) << 16);
    }
    if (ok) {
      #pragma unroll
      for (int t = 0; t < 4; ++t)
        ((uint4*)(rec + j*32))[t] = make_uint4(ow[4*t], ow[4*t+1], ow[4*t+2], ow[4*t+3]);
    }
  }
  // mean + GN stats
  float g1[4] = {0,0,0,0}, g2[4] = {0,0,0,0};
  #pragma unroll
  for (int k = 0; k < 32; ++k) {
    float m = msum[k] * (1.f/7.f);
    msum[k] = m;
    g1[k>>3] += m; g2[k>>3] += m*m;
  }
  if (ok) {
    u32 ow[16];
    #pragma unroll
    for (int i = 0; i < 16; ++i) ow[i] = (u32)f2bf(msum[2*i]) | ((u32)f2bf(msum[2*i+1]) << 16);
    u16* dst = mh + ((size_t)b*HW + (size_t)h*Ww + w)*128 + warp*32;
    #pragma unroll
    for (int t = 0; t < 4; ++t)
      ((uint4*)dst)[t] = make_uint4(ow[4*t], ow[4*t+1], ow[4*t+2], ow[4*t+3]);
  }
  #pragma unroll
  for (int g = 0; g < 4; ++g) {
    float a = g1[g], bb = g2[g];
    #pragma unroll
    for (int o = 32; o > 0; o >>= 1) { a += __shfl_down(a, o); bb += __shfl_down(bb, o); }
    if (lane == 0) {
      int gi = (b*16 + warp*4 + g)*2;
      atomicAdd(&gstats[gi],   a);
      atomicAdd(&gstats[gi+1], bb);
    }
  }
}

// ---------- pass A: group-norm -> lr into lrs[ch 0..128), zeros 176..192), per-pixel norm ----------
__global__ __launch_bounds__(256) void k_passA(const u16* __restrict__ mh, const float* __restrict__ gg,
    const float* __restrict__ gb, const float* __restrict__ gstats, u16* __restrict__ lrs, float* __restrict__ cn)
{
  __shared__ float sg[128], sb[128], smu[32], srs[32];
  int tid = threadIdx.x;
  if (tid < 128){ sg[tid] = gg[tid]; sb[tid] = gb[tid]; }
  else if (tid < 160){
    int i = tid-128;
    float s = gstats[2*i], s2 = gstats[2*i+1];
    float mu = s * (1.f/345600.f);
    float var = s2 * (1.f/345600.f) - mu*mu; if (var < 0.f) var = 0.f;
    smu[i] = mu; srs[i] = rsqrtf(var + 1e-5f);
  }
  __syncthreads();
  int p = blockIdx.x*256 + tid; if (p >= PIX) return;
  int b = p / HW, pix = p - b*HW, h = pix/Ww, w = pix - h*Ww;
  const uint4* src = (const uint4*)(mh + (size_t)p*128);
  u16* dst = lrs + ((size_t)(b*HP + h+1)*WP + (w+1))*ICP2;
  float ss = 0.f;
  #pragma unroll
  for (int t = 0; t < 16; ++t) {
    uint4 v = src[t];
    u32 wds[4] = {v.x, v.y, v.z, v.w};
    u32 ot[4];
    #pragma unroll
    for (int e = 0; e < 4; ++e) {
      int c0 = t*8 + e*2;
      int g0 = b*16 + (c0>>3);
      float a0 = (bflo(wds[e]) - smu[g0])*srs[g0]*sg[c0]   + sb[c0];
      float a1 = (bfhi(wds[e]) - smu[g0])*srs[g0]*sg[c0+1] + sb[c0+1];
      ss += a0*a0 + a1*a1;
      ot[e] = (u32)f2bf(a0) | ((u32)f2bf(a1) << 16);
    }
    ((uint4*)dst)[t] = make_uint4(ot[0], ot[1], ot[2], ot[3]);
  }
  uint4 z = make_uint4(0,0,0,0);
  ((uint4*)dst)[22] = z; ((uint4*)dst)[23] = z;      // channels 176..191
  cn[p] = fmaxf(sqrtf(ss), 1e-8f);
}

// ---------- pass B: 48 dilated cosine sims into lrs[ch 128..176) ----------
__global__ __launch_bounds__(256) void k_passB(u16* __restrict__ lrs, const float* __restrict__ cn)
{
  int p = blockIdx.x*256 + threadIdx.x; if (p >= PIX) return;
  int b = p / HW, pix = p - b*HW, h = pix/Ww, w = pix - h*Ww;
  u16* base = lrs + ((size_t)(b*HP + h+1)*WP + (w+1))*ICP2;
  uint4 own[16];
  #pragma unroll
  for (int t = 0; t < 16; ++t) own[t] = ((const uint4*)base)[t];
  float cnp = cn[p];
  u32 outw[24] __attribute__((aligned(16)));
  int k = 0;
  for (int i = 0; i < 7; ++i)
    for (int j = 0; j < 7; ++j) {
      if (i == 3 && j == 3) continue;
      int hq = h + 2*i - 6, wq = w + 2*j - 6;
      float sim = 0.f;
      if ((unsigned)hq < 120u && (unsigned)wq < 360u) {
        const u16* nb = lrs + ((size_t)(b*HP + hq+1)*WP + (wq+1))*ICP2;
        float dot = 0.f;
        #pragma unroll
        for (int t = 0; t < 16; ++t) {
          uint4 a = own[t]; uint4 c = ((const uint4*)nb)[t];
          dot += bflo(a.x)*bflo(c.x) + bfhi(a.x)*bfhi(c.x);
          dot += bflo(a.y)*bflo(c.y) + bfhi(a.y)*bfhi(c.y);
          dot += bflo(a.z)*bflo(c.z) + bfhi(a.z)*bfhi(c.z);
          dot += bflo(a.w)*bflo(c.w) + bfhi(a.w)*bfhi(c.w);
        }
        sim = dot / (cnp * cn[b*HW + hq*Ww + wq]);
      }
      u32 bv = f2bf(sim);
      if (k & 1) outw[k>>1] |= bv << 16; else outw[k>>1] = bv;
      ++k;
    }
  #pragma unroll
  for (int t = 0; t < 6; ++t) ((uint4*)(base + 128))[t] = ((uint4*)outw)[t];
}

// ---------- implicit-GEMM 3x3 conv, bf16 MFMA 16x16x32, BK=64 staging ----------
// A staged as 128-B record-chunks (XOR unit swizzle), 2 barriers per 64 ic.
// Tail super-chunk of conv1 reads 64B of neighbor-record garbage which
// multiplies the all-zero weight chunk 29 -> contributes exactly 0.
template<int NSUPER, int NCTOT, int ICPAD, int OC, int NWM, int NWN, bool RELU, bool OUTF32>
__global__ __launch_bounds__(256) void k_conv(const u16* __restrict__ inb, const u16* __restrict__ wf,
                                              const float* __restrict__ bias, void* __restrict__ outp)
{
  static_assert(NWM*NWN == 4, "4 waves");
  constexpr int WM = 8/NWM;
  constexpr int WN = (OC/16)/NWN;
  __shared__ __align__(16) u16 alds[4*66*64];      // 264 records x 128 B = 33,792 B
  const int wt = blockIdx.x, h2 = blockIdx.y, b = blockIdx.z;
  const int h0 = h2*2, w0 = wt*64;
  const int tid = threadIdx.x, wid = tid >> 6, lane = tid & 63;
  const int q = lane >> 4, n = lane & 15;
  const int mi = wid / NWN, ni = wid % NWN;

  f32x4 zz = {0.f,0.f,0.f,0.f};
  f32x4 acc[WM][WN];
  #pragma unroll
  for (int a = 0; a < WM; ++a)
    #pragma unroll
    for (int bq = 0; bq < WN; ++bq) acc[a][bq] = zz;

  const size_t pixbase = (size_t)(b*HP + h0)*WP + w0;

  for (int C = 0; C < NSUPER; ++C) {
    __syncthreads();
    {   // wave `wid` stages input row wid: 66 wc x 8 units of 16B, XOR-swizzled
      const int row = wid;
      const u16* gbase = inb + (pixbase + (size_t)row*WP)*ICPAD + C*64;
      #pragma unroll
      for (int o = 0; o < 9; ++o) {
        if (o < 8 || lane < 16) {
          int f = o*64 + lane;                  // 0..527
          int wc = f >> 3, us = f & 7;
          int ridx = row*66 + wc;
          int usrc = us ^ (ridx & 7);
          gl_lds16(gbase + (size_t)wc*ICPAD + usrc*8, alds + (row*528 + o*64)*8);
        }
      }
    }
    __syncthreads();
    #pragma unroll
    for (int s = 0; s < 2; ++s) {
      #pragma unroll
      for (int tap = 0; tap < 9; ++tap) {
        const int kh = tap/3, kw = tap%3;
        bf16x8 bfr[WN];
        #pragma unroll
        for (int gn = 0; gn < WN; ++gn) {
          int oc = (ni*WN + gn)*16 + n;
          bfr[gn] = *(const bf16x8*)(wf + (((size_t)tap*NCTOT + C*2+s)*OC + oc)*32 + q*8);
        }
        bf16x8 afr[WM];
        #pragma unroll
        for (int gm = 0; gm < WM; ++gm) {
          int G = mi*WM + gm;
          int idx = ((G>>2) + kh)*66 + (G&3)*16 + n + kw;
          int us = (s*4 + q) ^ (idx & 7);
          afr[gm] = *(const bf16x8*)(alds + (idx*8 + us)*8);
        }
        #pragma unroll
        for (int gm = 0; gm < WM; ++gm)
          #pragma unroll
          for (int gn = 0; gn < WN; ++gn)
            acc[gm][gn] = __builtin_amdgcn_mfma_f32_16x16x32_bf16(afr[gm], bfr[gn], acc[gm][gn], 0, 0, 0);
      }
    }
  }
  #pragma unroll
  for (int gn = 0; gn < WN; ++gn) {
    int oc = (ni*WN + gn)*16 + n;
    float bv = bias[oc];
    #pragma unroll
    for (int gm = 0; gm < WM; ++gm) {
      int G = mi*WM + gm;
      #pragma unroll
      for (int r = 0; r < 4; ++r) {
        int p = G*16 + q*4 + r;
        int w = w0 + (p & 63);
        if (w < Ww) {
          int h = h0 + (p >> 6);
          float v = acc[gm][gn][r] + bv;
          if (RELU) v = fmaxf(v, 0.f);
          size_t oi = ((size_t)(b*Hh + h)*Ww + w)*OC + oc;
          if (OUTF32) ((float*)outp)[oi] = v;
          else        ((u16*)outp)[oi]  = f2bf(v);
        }
      }
    }
  }
}

// ---------- deform-sample 3 offset sets + average, NCHW f32 out ----------
__device__ __forceinline__ void samp_add(float* acc, const u16* __restrict__ feat,
                                         int b, int h, int w, float ox, float oy, int c0)
{
  float ix = (float)w + ox, iy = (float)h + oy;
  float x0f = floorf(ix), y0f = floorf(iy);
  float wx = ix - x0f, wy = iy - y0f;
  int x0 = (int)x0f, y0 = (int)y0f;
  int x0c = min(max(x0, 0), 359),   x1c = min(max(x0+1, 0), 359);
  int y0c = min(max(y0, 0), 119),   y1c = min(max(y0+1, 0), 119);
  const u16* fb = feat + (size_t)b*HW*128 + c0;
  uint4 v00 = *(const uint4*)(fb + ((size_t)y0c*Ww + x0c)*128);
  uint4 v01 = *(const uint4*)(fb + ((size_t)y0c*Ww + x1c)*128);
  uint4 v10 = *(const uint4*)(fb + ((size_t)y1c*Ww + x0c)*128);
  uint4 v11 = *(const uint4*)(fb + ((size_t)y1c*Ww + x1c)*128);
  float w00 = (1.f-wx)*(1.f-wy), w01 = wx*(1.f-wy), w10 = (1.f-wx)*wy, w11 = wx*wy;
  u32 a00[4] = {v00.x,v00.y,v00.z,v00.w};
  u32 a01[4] = {v01.x,v01.y,v01.z,v01.w};
  u32 a10[4] = {v10.x,v10.y,v10.z,v10.w};
  u32 a11[4] = {v11.x,v11.y,v11.z,v11.w};
  #pragma unroll
  for (int e = 0; e < 4; ++e) {
    acc[2*e]   += w00*bflo(a00[e]) + w01*bflo(a01[e]) + w10*bflo(a10[e]) + w11*bflo(a11[e]);
    acc[2*e+1] += w00*bfhi(a00[e]) + w01*bfhi(a01[e]) + w10*bfhi(a10[e]) + w11*bfhi(a11[e]);
  }
}

__global__ __launch_bounds__(256) void k_sample(const u16* __restrict__ feat, const float* __restrict__ offs,
                                                float* __restrict__ out)
{
  int lane = threadIdx.x & 63;
  int cc = blockIdx.y*4 + (threadIdx.x >> 6);     // 0..15: 8-channel chunk
  int pix = blockIdx.x*64 + lane;                 // 675*64 = 43200 exact
  int b = blockIdx.z;
  int h = pix/Ww, w = pix - h*Ww;
  const float* ob = offs + ((size_t)b*HW + pix)*64;
  float acc[8] = {0,0,0,0,0,0,0,0};
  samp_add(acc, feat, b, h, w, ob[cc],          ob[16+cc],       cc*8);   // off0: 16 groups
  samp_add(acc, feat, b, h, w, ob[32+(cc>>1)],  ob[40+(cc>>1)],  cc*8);   // off1: 8 groups
  samp_add(acc, feat, b, h, w, ob[48+(cc>>2)],  ob[52+(cc>>2)],  cc*8);   // off2: 4 groups
  #pragma unroll
  for (int e = 0; e < 8; ++e)
    out[((size_t)(b*128 + cc*8 + e))*HW + pix] = acc[e] * (1.f/3.f);
}

// ---------- launch ----------
extern "C" void kernel_launch(void* const* d_in, const int* in_sizes, int n_in,
                              void* d_out, int out_size, void* d_ws, size_t ws_size,
                              hipStream_t stream)
{
  (void)in_sizes; (void)n_in; (void)out_size; (void)ws_size;
  const float* x      = (const float*)d_in[0];
  const float* conv_w = (const float*)d_in[1];
  const float* conv_b = (const float*)d_in[2];
  const float* gn_g   = (const float*)d_in[3];
  const float* gn_b   = (const float*)d_in[4];
  const float* off_w  = (const float*)d_in[5];
  const float* off_b  = (const float*)d_in[6];
  const float* off1_w = (const float*)d_in[7];
  const float* off1_b = (const float*)d_in[8];
  const float* off2_w = (const float*)d_in[9];
  const float* off2_b = (const float*)d_in[10];
  float* out = (float*)d_out;

  char* ws = (char*)d_ws;
  u16*   xh   = (u16*)(ws + OFF_XH);
  u16*   lrs  = (u16*)(ws + OFF_LRS);
  u16*   mh   = (u16*)(ws + OFF_FEAT);   // aliases feat (mh consumed in passA before conv writes feat)
  u16*   feat = mh;
  float* offs = (float*)(ws + OFF_XH);   // aliases xh (xh consumed by conv1 before conv2 writes offs)
  u16*   w1f  = (u16*)(ws + OFF_W1F);
  u16*   w2f  = (u16*)(ws + OFF_W2F);
  float* w2b  = (float*)(ws + OFF_W2B);
  float* cn   = (float*)(ws + OFF_CN);
  float* gst  = (float*)(ws + OFF_GST);

  k_init    <<<dim3(1055),      dim3(256), 0, stream>>>(xh, lrs, gst);
  k_prep_w1 <<<dim3(4320),      dim3(256), 0, stream>>>(conv_w, w1f);
  k_prep_w2 <<<dim3(432),       dim3(256), 0, stream>>>(off_w, off1_w, off2_w, off_b, off1_b, off2_b, w2f, w2b);
  k_packmean<<<dim3(6,120,2),   dim3(256), 0, stream>>>(x, xh, mh, gst);
  k_passA   <<<dim3(338),       dim3(256), 0, stream>>>(mh, gn_g, gn_b, gst, lrs, cn);
  k_passB   <<<dim3(338),       dim3(256), 0, stream>>>(lrs, cn);
  k_conv<15,30,ICP1,128,2,2,true ,false><<<dim3(6,60,2), dim3(256), 0, stream>>>(xh,  w1f, conv_b, feat);
  k_conv< 3, 6,ICP2, 64,4,1,false,true ><<<dim3(6,60,2), dim3(256), 0, stream>>>(lrs, w2f, w2b,   offs);
  k_sample  <<<dim3(675,4,2),   dim3(256), 0, stream>>>(feat, offs, out);
}

// Round 5
// 1249.711 us; speedup vs baseline: 1.3847x; 1.1362x over previous
//
#include <hip/hip_runtime.h>

typedef unsigned short u16;
typedef unsigned int   u32;
typedef short bf16x8 __attribute__((ext_vector_type(8)));
typedef float f32x4  __attribute__((ext_vector_type(4)));

// ---------- geometry ----------
#define Bn   2
#define Nn   7
#define Cc   128
#define Hh   120
#define Ww   360
#define HW   43200          // Hh*Ww
#define PIX  86400          // Bn*HW
#define HP   122            // padded H (h index +1)
#define WP   362            // padded W (w index +1)
#define ICP1 928            // 29*32 (898 real + pad)
#define ICP2 192            // 6*32  (176 real + pad)

// ---------- ws layout (bytes, 256-aligned) ----------
constexpr size_t AL(size_t x){ return (x + 255) & ~size_t(255); }
constexpr size_t XH_BYTES  = (size_t)Bn*HP*WP*ICP1*2;      // ~163.9 MB
constexpr size_t LRS_BYTES = (size_t)Bn*HP*WP*ICP2*2;      // ~33.9 MB
constexpr size_t OFF_XH  = 0;
constexpr size_t OFF_LRS = AL(OFF_XH + XH_BYTES + 65536);     // slack for conv A-tile overrun
constexpr size_t OFF_FEAT= AL(OFF_LRS + LRS_BYTES + 65536);   // feat aliases mh (mh dead before conv)
constexpr size_t OFF_W1F = AL(OFF_FEAT + (size_t)PIX*128*2);
constexpr size_t OFF_W2F = AL(OFF_W1F + (size_t)9*30*128*32*2);   // 30 chunks (29 real + zero pad)
constexpr size_t OFF_W2B = AL(OFF_W2F + (size_t)9*6*64*32*2);
constexpr size_t OFF_CN  = AL(OFF_W2B + 256);
constexpr size_t OFF_GST = AL(OFF_CN + (size_t)PIX*4);
// offsets buffer (f32, PIX*64*4 = 22.1MB) aliases xh (xh dead after main conv)

// ---------- helpers ----------
__device__ __forceinline__ float bf2f(u16 h){ union{u32 u; float f;} c; c.u = ((u32)h)<<16; return c.f; }
__device__ __forceinline__ u16 f2bf(float f){
  union{float f; u32 u;} c; c.f = f;
  u32 r = (c.u + 0x7FFFu + ((c.u>>16)&1u)) >> 16;
  return (u16)r;
}
__device__ __forceinline__ float bflo(u32 a){ union{u32 u; float f;} c; c.u = a<<16;          return c.f; }
__device__ __forceinline__ float bfhi(u32 a){ union{u32 u; float f;} c; c.u = a & 0xffff0000u; return c.f; }

__device__ __forceinline__ void gl_lds16(const u16* g, u16* l){
  __builtin_amdgcn_global_load_lds((const __attribute__((address_space(1))) void*)g,
                                   (__attribute__((address_space(3))) void*)l, 16, 0, 0);
}

// ---------- init: zero gstats + spatial pads of xh / lrs ----------
__global__ __launch_bounds__(256) void k_init(u16* __restrict__ xh, u16* __restrict__ lrs, float* __restrict__ gstats)
{
  int t = blockIdx.x*256 + threadIdx.x;
  if (t < 64) gstats[t] = 0.f;
  t -= 64;
  if (t < 0 || t >= 2*964*140) return;
  int b = t / (964*140); int r = t - b*(964*140);
  int i = r / 140, chunk = r - i*140;
  int hp, wp;
  if (i < 362)      { hp = 0;   wp = i; }
  else if (i < 724) { hp = 121; wp = i-362; }
  else { int j = i-724; hp = 1 + (j>>1); wp = (j&1) ? 361 : 0; }
  size_t pixel = (size_t)(b*HP + hp)*WP + wp;
  uint4 z = make_uint4(0,0,0,0);
  if (chunk < 116) ((uint4*)(xh  + pixel*ICP1))[chunk]      = z;
  else             ((uint4*)(lrs + pixel*ICP2))[chunk-116]  = z;
}

// ---------- weight prep: MFMA-fragment-ordered  [tap][chunk(30)][oc][32] ----------
__global__ __launch_bounds__(256) void k_prep_w1(const float* __restrict__ cw, u16* __restrict__ w1f)
{
  int t = blockIdx.x*256 + threadIdx.x;      // 9*30*128*32
  int kk = t & 31; int rest = t >> 5;
  int oc = rest & 127; rest >>= 7;           // rest = tap*30 + c
  int c = rest % 30, tap = rest / 30;
  int ic = c*32 + kk;
  u16 v = 0;
  if (ic < 898) v = f2bf(cw[(size_t)oc*8082 + (size_t)ic*9 + tap]);
  w1f[t] = v;
}

__global__ __launch_bounds__(256) void k_prep_w2(const float* __restrict__ ow0, const float* __restrict__ ow1,
    const float* __restrict__ ow2, const float* __restrict__ ob0, const float* __restrict__ ob1,
    const float* __restrict__ ob2, u16* __restrict__ w2f, float* __restrict__ w2b)
{
  int t = blockIdx.x*256 + threadIdx.x;      // 9*6*64*32
  if (t < 64) {
    float bv = 0.f;
    if (t < 32)      bv = ob0[t];
    else if (t < 48) bv = ob1[t-32];
    else if (t < 56) bv = ob2[t-48];
    w2b[t] = bv;
  }
  int kk = t & 31; int rest = t >> 5;
  int oc = rest & 63; rest >>= 6;            // rest = tap*6 + c
  int c = rest % 6, tap = rest / 6;
  int ic = c*32 + kk;
  u16 v = 0;
  if (ic < 176) {
    if (oc < 32)      v = f2bf(ow0[(size_t)oc*1584      + (size_t)ic*9 + tap]);
    else if (oc < 48) v = f2bf(ow1[(size_t)(oc-32)*1584 + (size_t)ic*9 + tap]);
    else if (oc < 56) v = f2bf(ow2[(size_t)(oc-48)*1584 + (size_t)ic*9 + tap]);
  }
  w2f[t] = v;
}

// ---------- fused pack + mean + GN stats, v2 ----------
// thread t = (cq=t>>4 channel-octet == GN group, wg=t&15 -> 4 w-pixels).
// float4 reads (1KB/inst), uint4 stores where one instruction covers
// 16 records x 256B fully contiguous. Mean local (thread holds all nn).
__global__ __launch_bounds__(256) void k_packmean(const float* __restrict__ x, u16* __restrict__ xh,
                                                  u16* __restrict__ mh, float* __restrict__ gstats)
{
  int wt = blockIdx.x, h = blockIdx.y, b = blockIdx.z;
  int t = threadIdx.x;
  int wg = t & 15, cq = t >> 4;
  int w0 = wt*64 + wg*4;
  bool ok = (w0 < Ww);                 // 4-pixel group all-valid or all-invalid
  int w0c = ok ? w0 : 0;
  const float* xb = x + (size_t)b*7*128*HW + (size_t)h*Ww + w0c;
  u16* recbase = xh + ((size_t)(b*HP + h+1)*WP + (w0c+1))*ICP1;

  float msum[8][4];
  #pragma unroll
  for (int c = 0; c < 8; ++c)
    #pragma unroll
    for (int s = 0; s < 4; ++s) msum[c][s] = 0.f;

  #pragma unroll
  for (int nn = 0; nn < 7; ++nn) {
    float4 v[8];
    const float* src = xb + (size_t)(nn*128 + cq*8)*HW;
    #pragma unroll
    for (int c = 0; c < 8; ++c)
      v[c] = ok ? *(const float4*)(src + (size_t)c*HW) : make_float4(0.f,0.f,0.f,0.f);
    #pragma unroll
    for (int c = 0; c < 8; ++c) {
      const float* vf = (const float*)&v[c];
      #pragma unroll
      for (int s = 0; s < 4; ++s) msum[c][s] += vf[s];
    }
    if (ok) {
      #pragma unroll
      for (int s = 0; s < 4; ++s) {
        u32 ow[4];
        #pragma unroll
        for (int e = 0; e < 4; ++e) {
          const float* lo = (const float*)&v[2*e];
          const float* hi = (const float*)&v[2*e+1];
          ow[e] = (u32)f2bf(lo[s]) | ((u32)f2bf(hi[s]) << 16);
        }
        *(uint4*)(recbase + (size_t)s*ICP1 + nn*128 + cq*8) = make_uint4(ow[0],ow[1],ow[2],ow[3]);
      }
    }
  }
  // mean -> mh, GN partials
  float g1 = 0.f, g2 = 0.f;
  #pragma unroll
  for (int c = 0; c < 8; ++c)
    #pragma unroll
    for (int s = 0; s < 4; ++s) {
      float m = msum[c][s] * (1.f/7.f);
      msum[c][s] = m;
      g1 += m; g2 += m*m;
    }
  if (ok) {
    #pragma unroll
    for (int s = 0; s < 4; ++s) {
      u32 ow[4];
      #pragma unroll
      for (int e = 0; e < 4; ++e)
        ow[e] = (u32)f2bf(msum[2*e][s]) | ((u32)f2bf(msum[2*e+1][s]) << 16);
      *(uint4*)(mh + ((size_t)b*HW + (size_t)h*Ww + w0 + s)*128 + cq*8) = make_uint4(ow[0],ow[1],ow[2],ow[3]);
    }
  }
  #pragma unroll
  for (int o = 8; o > 0; o >>= 1) { g1 += __shfl_down(g1, o, 16); g2 += __shfl_down(g2, o, 16); }
  if (wg == 0) {
    int gi = (b*16 + cq)*2;
    atomicAdd(&gstats[gi],   g1);
    atomicAdd(&gstats[gi+1], g2);
  }
  // coords + zero pad (chunk 28): wave 0, one record per lane
  if (t < 64) {
    int w = wt*64 + t;
    if (w < Ww) {
      u16* rc = xh + ((size_t)(b*HP + h+1)*WP + (w+1))*ICP1 + 896;
      u32 cw0 = (u32)f2bf((float)w*(2.f/359.f) - 1.f) | ((u32)f2bf((float)h*(2.f/119.f) - 1.f) << 16);
      ((uint4*)rc)[0] = make_uint4(cw0, 0, 0, 0);
      ((uint4*)rc)[1] = make_uint4(0,0,0,0);
      ((uint4*)rc)[2] = make_uint4(0,0,0,0);
      ((uint4*)rc)[3] = make_uint4(0,0,0,0);
    }
  }
}

// ---------- pass A: group-norm -> lr into lrs[ch 0..128), zeros 176..192), per-pixel norm ----------
__global__ __launch_bounds__(256) void k_passA(const u16* __restrict__ mh, const float* __restrict__ gg,
    const float* __restrict__ gb, const float* __restrict__ gstats, u16* __restrict__ lrs, float* __restrict__ cn)
{
  __shared__ float sg[128], sb[128], smu[32], srs[32];
  int tid = threadIdx.x;
  if (tid < 128){ sg[tid] = gg[tid]; sb[tid] = gb[tid]; }
  else if (tid < 160){
    int i = tid-128;
    float s = gstats[2*i], s2 = gstats[2*i+1];
    float mu = s * (1.f/345600.f);
    float var = s2 * (1.f/345600.f) - mu*mu; if (var < 0.f) var = 0.f;
    smu[i] = mu; srs[i] = rsqrtf(var + 1e-5f);
  }
  __syncthreads();
  int p = blockIdx.x*256 + tid; if (p >= PIX) return;
  int b = p / HW, pix = p - b*HW, h = pix/Ww, w = pix - h*Ww;
  const uint4* src = (const uint4*)(mh + (size_t)p*128);
  u16* dst = lrs + ((size_t)(b*HP + h+1)*WP + (w+1))*ICP2;
  float ss = 0.f;
  #pragma unroll
  for (int t = 0; t < 16; ++t) {
    uint4 v = src[t];
    u32 wds[4] = {v.x, v.y, v.z, v.w};
    u32 ot[4];
    #pragma unroll
    for (int e = 0; e < 4; ++e) {
      int c0 = t*8 + e*2;
      int g0 = b*16 + (c0>>3);
      float a0 = (bflo(wds[e]) - smu[g0])*srs[g0]*sg[c0]   + sb[c0];
      float a1 = (bfhi(wds[e]) - smu[g0])*srs[g0]*sg[c0+1] + sb[c0+1];
      ss += a0*a0 + a1*a1;
      ot[e] = (u32)f2bf(a0) | ((u32)f2bf(a1) << 16);
    }
    ((uint4*)dst)[t] = make_uint4(ot[0], ot[1], ot[2], ot[3]);
  }
  uint4 z = make_uint4(0,0,0,0);
  ((uint4*)dst)[22] = z; ((uint4*)dst)[23] = z;      // channels 176..191
  cn[p] = fmaxf(sqrtf(ss), 1e-8f);
}

// ---------- pass B: 48 dilated cosine sims into lrs[ch 128..176) ----------
__global__ __launch_bounds__(256) void k_passB(u16* __restrict__ lrs, const float* __restrict__ cn)
{
  int p = blockIdx.x*256 + threadIdx.x; if (p >= PIX) return;
  int b = p / HW, pix = p - b*HW, h = pix/Ww, w = pix - h*Ww;
  u16* base = lrs + ((size_t)(b*HP + h+1)*WP + (w+1))*ICP2;
  uint4 own[16];
  #pragma unroll
  for (int t = 0; t < 16; ++t) own[t] = ((const uint4*)base)[t];
  float cnp = cn[p];
  u32 outw[24] __attribute__((aligned(16)));
  int k = 0;
  for (int i = 0; i < 7; ++i)
    for (int j = 0; j < 7; ++j) {
      if (i == 3 && j == 3) continue;
      int hq = h + 2*i - 6, wq = w + 2*j - 6;
      float sim = 0.f;
      if ((unsigned)hq < 120u && (unsigned)wq < 360u) {
        const u16* nb = lrs + ((size_t)(b*HP + hq+1)*WP + (wq+1))*ICP2;
        float dot = 0.f;
        #pragma unroll
        for (int t = 0; t < 16; ++t) {
          uint4 a = own[t]; uint4 c = ((const uint4*)nb)[t];
          dot += bflo(a.x)*bflo(c.x) + bfhi(a.x)*bfhi(c.x);
          dot += bflo(a.y)*bflo(c.y) + bfhi(a.y)*bfhi(c.y);
          dot += bflo(a.z)*bflo(c.z) + bfhi(a.z)*bfhi(c.z);
          dot += bflo(a.w)*bflo(c.w) + bfhi(a.w)*bfhi(c.w);
        }
        sim = dot / (cnp * cn[b*HW + hq*Ww + wq]);
      }
      u32 bv = f2bf(sim);
      if (k & 1) outw[k>>1] |= bv << 16; else outw[k>>1] = bv;
      ++k;
    }
  #pragma unroll
  for (int t = 0; t < 6; ++t) ((uint4*)(base + 128))[t] = ((uint4*)outw)[t];
}

// ---------- implicit-GEMM 3x3 conv, bf16 MFMA 16x16x32, BK=64 staging ----------
template<int NSUPER, int NCTOT, int ICPAD, int OC, int NWM, int NWN, bool RELU, bool OUTF32>
__global__ __launch_bounds__(256) void k_conv(const u16* __restrict__ inb, const u16* __restrict__ wf,
                                              const float* __restrict__ bias, void* __restrict__ outp)
{
  static_assert(NWM*NWN == 4, "4 waves");
  constexpr int WM = 8/NWM;
  constexpr int WN = (OC/16)/NWN;
  __shared__ __align__(16) u16 alds[4*66*64];      // 264 records x 128 B = 33,792 B
  const int wt = blockIdx.x, h2 = blockIdx.y, b = blockIdx.z;
  const int h0 = h2*2, w0 = wt*64;
  const int tid = threadIdx.x, wid = tid >> 6, lane = tid & 63;
  const int q = lane >> 4, n = lane & 15;
  const int mi = wid / NWN, ni = wid % NWN;

  f32x4 zz = {0.f,0.f,0.f,0.f};
  f32x4 acc[WM][WN];
  #pragma unroll
  for (int a = 0; a < WM; ++a)
    #pragma unroll
    for (int bq = 0; bq < WN; ++bq) acc[a][bq] = zz;

  const size_t pixbase = (size_t)(b*HP + h0)*WP + w0;

  for (int C = 0; C < NSUPER; ++C) {
    __syncthreads();
    {   // wave `wid` stages input row wid: 66 wc x 8 units of 16B, XOR-swizzled
      const int row = wid;
      const u16* gbase = inb + (pixbase + (size_t)row*WP)*ICPAD + C*64;
      #pragma unroll
      for (int o = 0; o < 9; ++o) {
        if (o < 8 || lane < 16) {
          int f = o*64 + lane;                  // 0..527
          int wc = f >> 3, us = f & 7;
          int ridx = row*66 + wc;
          int usrc = us ^ (ridx & 7);
          gl_lds16(gbase + (size_t)wc*ICPAD + usrc*8, alds + (row*528 + o*64)*8);
        }
      }
    }
    __syncthreads();
    #pragma unroll
    for (int s = 0; s < 2; ++s) {
      #pragma unroll
      for (int tap = 0; tap < 9; ++tap) {
        const int kh = tap/3, kw = tap%3;
        bf16x8 bfr[WN];
        #pragma unroll
        for (int gn = 0; gn < WN; ++gn) {
          int oc = (ni*WN + gn)*16 + n;
          bfr[gn] = *(const bf16x8*)(wf + (((size_t)tap*NCTOT + C*2+s)*OC + oc)*32 + q*8);
        }
        bf16x8 afr[WM];
        #pragma unroll
        for (int gm = 0; gm < WM; ++gm) {
          int G = mi*WM + gm;
          int idx = ((G>>2) + kh)*66 + (G&3)*16 + n + kw;
          int us = (s*4 + q) ^ (idx & 7);
          afr[gm] = *(const bf16x8*)(alds + (idx*8 + us)*8);
        }
        #pragma unroll
        for (int gm = 0; gm < WM; ++gm)
          #pragma unroll
          for (int gn = 0; gn < WN; ++gn)
            acc[gm][gn] = __builtin_amdgcn_mfma_f32_16x16x32_bf16(afr[gm], bfr[gn], acc[gm][gn], 0, 0, 0);
      }
    }
  }
  #pragma unroll
  for (int gn = 0; gn < WN; ++gn) {
    int oc = (ni*WN + gn)*16 + n;
    float bv = bias[oc];
    #pragma unroll
    for (int gm = 0; gm < WM; ++gm) {
      int G = mi*WM + gm;
      #pragma unroll
      for (int r = 0; r < 4; ++r) {
        int p = G*16 + q*4 + r;
        int w = w0 + (p & 63);
        if (w < Ww) {
          int h = h0 + (p >> 6);
          float v = acc[gm][gn][r] + bv;
          if (RELU) v = fmaxf(v, 0.f);
          size_t oi = ((size_t)(b*Hh + h)*Ww + w)*OC + oc;
          if (OUTF32) ((float*)outp)[oi] = v;
          else        ((u16*)outp)[oi]  = f2bf(v);
        }
      }
    }
  }
}

// ---------- deform-sample 3 offset sets + average, NCHW f32 out ----------
__device__ __forceinline__ void samp_add(float* acc, const u16* __restrict__ feat,
                                         int b, int h, int w, float ox, float oy, int c0)
{
  float ix = (float)w + ox, iy = (float)h + oy;
  float x0f = floorf(ix), y0f = floorf(iy);
  float wx = ix - x0f, wy = iy - y0f;
  int x0 = (int)x0f, y0 = (int)y0f;
  int x0c = min(max(x0, 0), 359),   x1c = min(max(x0+1, 0), 359);
  int y0c = min(max(y0, 0), 119),   y1c = min(max(y0+1, 0), 119);
  const u16* fb = feat + (size_t)b*HW*128 + c0;
  uint4 v00 = *(const uint4*)(fb + ((size_t)y0c*Ww + x0c)*128);
  uint4 v01 = *(const uint4*)(fb + ((size_t)y0c*Ww + x1c)*128);
  uint4 v10 = *(const uint4*)(fb + ((size_t)y1c*Ww + x0c)*128);
  uint4 v11 = *(const uint4*)(fb + ((size_t)y1c*Ww + x1c)*128);
  float w00 = (1.f-wx)*(1.f-wy), w01 = wx*(1.f-wy), w10 = (1.f-wx)*wy, w11 = wx*wy;
  u32 a00[4] = {v00.x,v00.y,v00.z,v00.w};
  u32 a01[4] = {v01.x,v01.y,v01.z,v01.w};
  u32 a10[4] = {v10.x,v10.y,v10.z,v10.w};
  u32 a11[4] = {v11.x,v11.y,v11.z,v11.w};
  #pragma unroll
  for (int e = 0; e < 4; ++e) {
    acc[2*e]   += w00*bflo(a00[e]) + w01*bflo(a01[e]) + w10*bflo(a10[e]) + w11*bflo(a11[e]);
    acc[2*e+1] += w00*bfhi(a00[e]) + w01*bfhi(a01[e]) + w10*bfhi(a10[e]) + w11*bfhi(a11[e]);
  }
}

__global__ __launch_bounds__(256) void k_sample(const u16* __restrict__ feat, const float* __restrict__ offs,
                                                float* __restrict__ out)
{
  int lane = threadIdx.x & 63;
  int cc = blockIdx.y*4 + (threadIdx.x >> 6);     // 0..15: 8-channel chunk
  int pix = blockIdx.x*64 + lane;                 // 675*64 = 43200 exact
  int b = blockIdx.z;
  int h = pix/Ww, w = pix - h*Ww;
  const float* ob = offs + ((size_t)b*HW + pix)*64;
  float acc[8] = {0,0,0,0,0,0,0,0};
  samp_add(acc, feat, b, h, w, ob[cc],          ob[16+cc],       cc*8);   // off0: 16 groups
  samp_add(acc, feat, b, h, w, ob[32+(cc>>1)],  ob[40+(cc>>1)],  cc*8);   // off1: 8 groups
  samp_add(acc, feat, b, h, w, ob[48+(cc>>2)],  ob[52+(cc>>2)],  cc*8);   // off2: 4 groups
  #pragma unroll
  for (int e = 0; e < 8; ++e)
    out[((size_t)(b*128 + cc*8 + e))*HW + pix] = acc[e] * (1.f/3.f);
}

// ---------- launch ----------
extern "C" void kernel_launch(void* const* d_in, const int* in_sizes, int n_in,
                              void* d_out, int out_size, void* d_ws, size_t ws_size,
                              hipStream_t stream)
{
  (void)in_sizes; (void)n_in; (void)out_size; (void)ws_size;
  const float* x      = (const float*)d_in[0];
  const float* conv_w = (const float*)d_in[1];
  const float* conv_b = (const float*)d_in[2];
  const float* gn_g   = (const float*)d_in[3];
  const float* gn_b   = (const float*)d_in[4];
  const float* off_w  = (const float*)d_in[5];
  const float* off_b  = (const float*)d_in[6];
  const float* off1_w = (const float*)d_in[7];
  const float* off1_b = (const float*)d_in[8];
  const float* off2_w = (const float*)d_in[9];
  const float* off2_b = (const float*)d_in[10];
  float* out = (float*)d_out;

  char* ws = (char*)d_ws;
  u16*   xh   = (u16*)(ws + OFF_XH);
  u16*   lrs  = (u16*)(ws + OFF_LRS);
  u16*   mh   = (u16*)(ws + OFF_FEAT);   // aliases feat (mh consumed in passA before conv writes feat)
  u16*   feat = mh;
  float* offs = (float*)(ws + OFF_XH);   // aliases xh (xh consumed by conv1 before conv2 writes offs)
  u16*   w1f  = (u16*)(ws + OFF_W1F);
  u16*   w2f  = (u16*)(ws + OFF_W2F);
  float* w2b  = (float*)(ws + OFF_W2B);
  float* cn   = (float*)(ws + OFF_CN);
  float* gst  = (float*)(ws + OFF_GST);

  k_init    <<<dim3(1055),      dim3(256), 0, stream>>>(xh, lrs, gst);
  k_prep_w1 <<<dim3(4320),      dim3(256), 0, stream>>>(conv_w, w1f);
  k_prep_w2 <<<dim3(432),       dim3(256), 0, stream>>>(off_w, off1_w, off2_w, off_b, off1_b, off2_b, w2f, w2b);
  k_packmean<<<dim3(6,120,2),   dim3(256), 0, stream>>>(x, xh, mh, gst);
  k_passA   <<<dim3(338),       dim3(256), 0, stream>>>(mh, gn_g, gn_b, gst, lrs, cn);
  k_passB   <<<dim3(338),       dim3(256), 0, stream>>>(lrs, cn);
  k_conv<15,30,ICP1,128,2,2,true ,false><<<dim3(6,60,2), dim3(256), 0, stream>>>(xh,  w1f, conv_b, feat);
  k_conv< 3, 6,ICP2, 64,4,1,false,true ><<<dim3(6,60,2), dim3(256), 0, stream>>>(lrs, w2f, w2b,   offs);
  k_sample  <<<dim3(675,4,2),   dim3(256), 0, stream>>>(feat, offs, out);
}